// Round 13
// baseline (627.320 us; speedup 1.0000x reference)
//
#include <hip/hip_runtime.h>

#define D_IN  64
#define E_W   16
#define D_MSG 80
#define NXCD  8

static __device__ __forceinline__ void f4add(float4& a, const float4& b) {
    a.x += b.x; a.y += b.y; a.z += b.z; a.w += b.w;
}

// ---------------------------------------------------------------------------
// CSR build step 1: degree histogram, XCD-sharded (round-9, verified).
// ---------------------------------------------------------------------------
__global__ __launch_bounds__(256) void k_hist_sh(const int4* __restrict__ dst4,
                                                 const int* __restrict__ dst,
                                                 int* __restrict__ deg,
                                                 int E, int rng)
{
    int shard = blockIdx.x & (NXCD - 1);
    int wg    = blockIdx.x / NXCD;
    int lo    = shard * rng;
    int hi    = lo + rng;
    int E4    = E >> 2;

    int base = wg * 512;
    int stop = min(base + 512, E4);
    for (int i = base + threadIdx.x; i < stop; i += 256) {
        int4 d = dst4[i];
        if (d.x >= lo && d.x < hi) atomicAdd(deg + d.x, 1);
        if (d.y >= lo && d.y < hi) atomicAdd(deg + d.y, 1);
        if (d.z >= lo && d.z < hi) atomicAdd(deg + d.z, 1);
        if (d.w >= lo && d.w < hi) atomicAdd(deg + d.w, 1);
    }
    if (wg == 0 && threadIdx.x < (E & 3)) {
        int e = (E & ~3) + threadIdx.x;
        int d = dst[e];
        if (d >= lo && d < hi) atomicAdd(deg + d, 1);
    }
}

// ---------------------------------------------------------------------------
// CSR build step 2: SINGLE-dispatch exclusive scan (replaces scan1/2/3).
// 1024 threads; thread t serially sums its contiguous chunk, LDS
// Hillis-Steele over 1024 partials, then writes offsets+cursor.
// 400KB of deg traffic, L2-hot -> few us; saves 2 dispatch overheads.
// ---------------------------------------------------------------------------
__global__ __launch_bounds__(1024) void k_scan_one(const int* __restrict__ deg,
                                                   int* __restrict__ offsets,
                                                   int* __restrict__ cursor,
                                                   int n, int E)
{
    __shared__ int ts[1024];
    const int C = (n + 1023) / 1024;
    int t  = threadIdx.x;
    int lo = t * C;
    int hi = min(lo + C, n);

    int s = 0;
    for (int i = lo; i < hi; ++i) s += deg[i];
    ts[t] = s; __syncthreads();
    #pragma unroll
    for (int off = 1; off < 1024; off <<= 1) {
        int v = (t >= off) ? ts[t - off] : 0;
        __syncthreads();
        ts[t] += v;
        __syncthreads();
    }
    int run = ts[t] - s;
    for (int i = lo; i < hi; ++i) {
        int d = deg[i];
        offsets[i] = run;
        cursor[i]  = run;
        run += d;
    }
    if (t == 0) offsets[n] = E;
}

// ---------------------------------------------------------------------------
// CSR build step 3: scatter (src,eid) into dst-sorted order, XCD-sharded
// (round-9 verified; round-11 ew-payload fold regressed: 2x write amp).
// ---------------------------------------------------------------------------
__global__ __launch_bounds__(256) void k_reorder_sh(const int4* __restrict__ src4,
                                                    const int4* __restrict__ dst4,
                                                    const int* __restrict__ src,
                                                    const int* __restrict__ dst,
                                                    int* __restrict__ cursor,
                                                    int2* __restrict__ sorted,
                                                    int E, int rng)
{
    int shard = blockIdx.x & (NXCD - 1);
    int wg    = blockIdx.x / NXCD;
    int lo    = shard * rng;
    int hi    = lo + rng;
    int E4    = E >> 2;

    int base = wg * 512;
    int stop = min(base + 512, E4);
    for (int i = base + threadIdx.x; i < stop; i += 256) {
        int4 d = dst4[i];
        bool any = (d.x >= lo && d.x < hi) | (d.y >= lo && d.y < hi) |
                   (d.z >= lo && d.z < hi) | (d.w >= lo && d.w < hi);
        if (!any) continue;
        int4 s = src4[i];
        int e = i * 4;
        if (d.x >= lo && d.x < hi) sorted[atomicAdd(cursor + d.x, 1)] = make_int2(s.x, e + 0);
        if (d.y >= lo && d.y < hi) sorted[atomicAdd(cursor + d.y, 1)] = make_int2(s.y, e + 1);
        if (d.z >= lo && d.z < hi) sorted[atomicAdd(cursor + d.z, 1)] = make_int2(s.z, e + 2);
        if (d.w >= lo && d.w < hi) sorted[atomicAdd(cursor + d.w, 1)] = make_int2(s.w, e + 3);
    }
    if (wg == 0 && threadIdx.x < (E & 3)) {
        int e = (E & ~3) + threadIdx.x;
        int d = dst[e];
        if (d >= lo && d < hi) sorted[atomicAdd(cursor + d, 1)] = make_int2(src[e], e);
    }
}

// ---------------------------------------------------------------------------
// FUSED pull + GEMM + ReLU. 256 threads = 16 nodes x 16 lanes.
// Phase 1 (pull): lane l of node nl gathers feat4[src] + ew4[eid] (unroll-4),
//   x row (80 floats) staged to LDS.
// Phase 2 (gemm): thread (nl,l) computes out[node][4l..4l+3] from LDS x + W.
//   320 FMA/thread hides under the gather stream (round-12: VALUBusy 10%).
// Saves: gemm dispatch, acc_h write+read (57MB), acc_w round-trip (13MB),
//   gemm's feat re-read (26MB).
// LDS 26KB -> 6 blocks/CU, ~same occupancy as round-12 pull (77%).
// ---------------------------------------------------------------------------
__global__ __launch_bounds__(256) void k_pull_gemm(const float4* __restrict__ feat4,
                                                   const float4* __restrict__ ew4,
                                                   const int2* __restrict__ sorted,
                                                   const int* __restrict__ offsets,
                                                   const float* __restrict__ Wm,
                                                   const float* __restrict__ bias,
                                                   float4* __restrict__ out4, int N)
{
    __shared__ float4 Wl[D_MSG * 16];   // [k][l] : 20KB
    __shared__ float4 bl4[16];
    __shared__ float  xs[16 * 84];      // 16 node rows, padded : 5.4KB

    for (int i = threadIdx.x; i < D_MSG * 16; i += 256)
        Wl[i] = ((const float4*)Wm)[i];
    if (threadIdx.x < 16)
        bl4[threadIdx.x] = ((const float4*)bias)[threadIdx.x];

    const int nl   = threadIdx.x >> 4;
    const int l    = threadIdx.x & 15;
    const int node = blockIdx.x * 16 + nl;

    if (node < N) {
        int beg = offsets[node];
        int end = offsets[node + 1];

        float4 ah = feat4[(size_t)node * 16 + l];   // eps-residual (EPS=0)
        float4 aw = make_float4(0.f, 0.f, 0.f, 0.f);

        int p = beg;
        for (; p + 4 <= end; p += 4) {
            int2 r0 = sorted[p + 0];
            int2 r1 = sorted[p + 1];
            int2 r2 = sorted[p + 2];
            int2 r3 = sorted[p + 3];
            float4 f0 = feat4[(size_t)r0.x * 16 + l];
            float4 f1 = feat4[(size_t)r1.x * 16 + l];
            float4 f2 = feat4[(size_t)r2.x * 16 + l];
            float4 f3 = feat4[(size_t)r3.x * 16 + l];
            if (l < 4) {
                float4 w0 = ew4[(size_t)r0.y * 4 + l];
                float4 w1 = ew4[(size_t)r1.y * 4 + l];
                float4 w2 = ew4[(size_t)r2.y * 4 + l];
                float4 w3 = ew4[(size_t)r3.y * 4 + l];
                f4add(aw, w0); f4add(aw, w1); f4add(aw, w2); f4add(aw, w3);
            }
            f4add(ah, f0); f4add(ah, f1); f4add(ah, f2); f4add(ah, f3);
        }
        for (; p < end; ++p) {
            int2 r = sorted[p];
            f4add(ah, feat4[(size_t)r.x * 16 + l]);
            if (l < 4) f4add(aw, ew4[(size_t)r.y * 4 + l]);
        }

        *(float4*)&xs[nl * 84 + l * 4] = ah;           // byte 336*nl+16*l, 16B-aligned
        if (l < 4) *(float4*)&xs[nl * 84 + 64 + l * 4] = aw;
    }
    __syncthreads();

    if (node < N) {
        float4 acc = bl4[l];
        #pragma unroll 8
        for (int k = 0; k < D_MSG; ++k) {
            float  xk = xs[nl * 84 + k];               // broadcast within nl-group
            float4 w  = Wl[k * 16 + l];                // 2-way bank alias = free
            acc.x += xk * w.x;
            acc.y += xk * w.y;
            acc.z += xk * w.z;
            acc.w += xk * w.w;
        }
        acc.x = fmaxf(acc.x, 0.f);
        acc.y = fmaxf(acc.y, 0.f);
        acc.z = fmaxf(acc.z, 0.f);
        acc.w = fmaxf(acc.w, 0.f);
        out4[(size_t)node * 16 + l] = acc;
    }
}

// ---------------------------------------------------------------------------
// Last-resort fallback: atomic scatter (+ separate gemm with add_feat).
// ---------------------------------------------------------------------------
__global__ __launch_bounds__(256) void scatter_kernel(
    const float4* __restrict__ feat4, const float4* __restrict__ ew4,
    const int* __restrict__ src, const int* __restrict__ dst,
    float* __restrict__ acc_h, float* __restrict__ acc_w, int E)
{
    int t = blockIdx.x * 256 + threadIdx.x;
    int e = t >> 4;
    if (e >= E) return;
    int l = t & 15;
    int s = src[e];
    int d = dst[e];
    float4 hv = feat4[(size_t)s * 16 + l];
    float4 wv;
    bool do_w = (l < 4);
    if (do_w) wv = ew4[(size_t)e * 4 + l];
    float* p = acc_h + (size_t)d * D_IN + l * 4;
    unsafeAtomicAdd(p + 0, hv.x);
    unsafeAtomicAdd(p + 1, hv.y);
    unsafeAtomicAdd(p + 2, hv.z);
    unsafeAtomicAdd(p + 3, hv.w);
    if (do_w) {
        float* q = acc_w + (size_t)d * E_W + l * 4;
        unsafeAtomicAdd(q + 0, wv.x);
        unsafeAtomicAdd(q + 1, wv.y);
        unsafeAtomicAdd(q + 2, wv.z);
        unsafeAtomicAdd(q + 3, wv.w);
    }
}

__global__ __launch_bounds__(256) void gemm_relu_kernel(
    const float* __restrict__ feat, const float* __restrict__ acc_w,
    const float* __restrict__ Wm, const float* __restrict__ bias,
    float* __restrict__ out, int N, int add_feat)
{
    __shared__ float4 Wl[D_MSG * 16];
    __shared__ float4 bl4[16];
    __shared__ float  xs[64 * 84];

    for (int i = threadIdx.x; i < D_MSG * 16; i += 256)
        Wl[i] = ((const float4*)Wm)[i];
    if (threadIdx.x < 16)
        bl4[threadIdx.x] = ((const float4*)bias)[threadIdx.x];

    const int tc   = threadIdx.x & 15;
    const int tg   = threadIdx.x >> 4;
    const int base = blockIdx.x * 64;

    for (int i = threadIdx.x; i < 64 * 20; i += 256) {
        int r = i / 20, c = i % 20;
        int row = base + r;
        float4 v = make_float4(0.f, 0.f, 0.f, 0.f);
        if (row < N) {
            if (c < 16) {
                v = ((const float4*)out)[(size_t)row * 16 + c];
                if (add_feat) {
                    float4 f = ((const float4*)feat)[(size_t)row * 16 + c];
                    f4add(v, f);
                }
            } else {
                v = ((const float4*)acc_w)[(size_t)row * 4 + (c - 16)];
            }
        }
        *((float4*)&xs[r * 84 + c * 4]) = v;
    }
    __syncthreads();

    float4 ob = bl4[tc];
    float4 acc[4];
    acc[0] = ob; acc[1] = ob; acc[2] = ob; acc[3] = ob;

    #pragma unroll 4
    for (int k = 0; k < D_MSG; ++k) {
        float4 w = Wl[k * 16 + tc];
        #pragma unroll
        for (int rr = 0; rr < 4; ++rr) {
            float xk = xs[(tg * 4 + rr) * 84 + k];
            acc[rr].x += xk * w.x;
            acc[rr].y += xk * w.y;
            acc[rr].z += xk * w.z;
            acc[rr].w += xk * w.w;
        }
    }

    #pragma unroll
    for (int rr = 0; rr < 4; ++rr) {
        int row = base + tg * 4 + rr;
        if (row < N) {
            float4 v = acc[rr];
            v.x = fmaxf(v.x, 0.f);
            v.y = fmaxf(v.y, 0.f);
            v.z = fmaxf(v.z, 0.f);
            v.w = fmaxf(v.w, 0.f);
            ((float4*)out)[(size_t)row * 16 + tc] = v;
        }
    }
}

static inline size_t align256(size_t x) { return (x + 255) & ~(size_t)255; }

extern "C" void kernel_launch(void* const* d_in, const int* in_sizes, int n_in,
                              void* d_out, int out_size, void* d_ws, size_t ws_size,
                              hipStream_t stream) {
    const float* feat   = (const float*)d_in[0];
    const float* edge_w = (const float*)d_in[1];
    const float* Wm     = (const float*)d_in[2];
    const float* bias   = (const float*)d_in[3];
    const int*   src    = (const int*)d_in[4];
    const int*   dst    = (const int*)d_in[5];
    float* out = (float*)d_out;

    const int N = in_sizes[0] / D_IN;
    const int E = in_sizes[4];

    // ---- workspace layout (round-9 compatible; acc_w only for fallback) ----
    size_t o_accw   = 0;
    size_t o_deg    = align256(o_accw + (size_t)N * E_W * 4);
    size_t o_excl   = align256(o_deg  + (size_t)(N + 1) * 4);
    size_t o_off    = align256(o_excl + (size_t)N * 4);
    size_t o_cur    = align256(o_off  + (size_t)(N + 1) * 4);
    size_t o_bsum   = align256(o_cur  + (size_t)N * 4);
    size_t o_bexcl  = align256(o_bsum + 256 * 4);
    size_t o_sorted = align256(o_bexcl + 256 * 4);
    size_t need     = o_sorted + (size_t)E * 8;

    char* ws = (char*)d_ws;
    float* acc_w = (float*)(ws + o_accw);

    if (ws_size >= need) {
        int*  deg     = (int*) (ws + o_deg);
        int*  offsets = (int*) (ws + o_off);
        int*  cursor  = (int*) (ws + o_cur);
        int2* sorted  = (int2*)(ws + o_sorted);

        hipMemsetAsync(deg, 0, (size_t)(N + 1) * 4, stream);

        const int rng = (N + NXCD - 1) / NXCD;
        const int E4  = E >> 2;
        const int wg_per_shard = (E4 + 511) / 512;
        const int grid_sh = wg_per_shard * NXCD;

        k_hist_sh<<<grid_sh, 256, 0, stream>>>((const int4*)dst, dst, deg, E, rng);

        k_scan_one<<<1, 1024, 0, stream>>>(deg, offsets, cursor, N, E);

        k_reorder_sh<<<grid_sh, 256, 0, stream>>>(
            (const int4*)src, (const int4*)dst, src, dst, cursor, sorted, E, rng);

        k_pull_gemm<<<(N + 15) / 16, 256, 0, stream>>>(
            (const float4*)feat, (const float4*)edge_w, sorted, offsets,
            Wm, bias, (float4*)out, N);
    } else {
        hipMemsetAsync(d_out, 0, (size_t)N * D_IN * sizeof(float), stream);
        hipMemsetAsync(acc_w, 0, (size_t)N * E_W * sizeof(float), stream);
        long long tot = (long long)E * 16;
        scatter_kernel<<<(int)((tot + 255) / 256), 256, 0, stream>>>(
            (const float4*)feat, (const float4*)edge_w, src, dst, out, acc_w, E);
        gemm_relu_kernel<<<(N + 63) / 64, 256, 0, stream>>>(
            feat, acc_w, Wm, bias, out, N, 1);
    }
}